// Round 9
// baseline (562.875 us; speedup 1.0000x reference)
//
#include <hip/hip_runtime.h>
#include <hip/hip_bf16.h>

#define NN 16384
#define DD 256
#define BM 256
#define BN 256
#define BK 64
#define JW 4                   // bcol tiles walked per block
#define NS 16                  // JW * (DD/BK) tile-steps per block
#define THREADS 512
#define SHIFT_C 64.0f
#define LOG2E 1.4426950408889634f

typedef __attribute__((ext_vector_type(4))) float f32x4;
typedef __attribute__((ext_vector_type(8))) short bf16x8;

#if __has_builtin(__builtin_amdgcn_exp2f)
#define EXP2F(x) __builtin_amdgcn_exp2f(x)
#else
#define EXP2F(x) exp2f(x)
#endif

__device__ __forceinline__ unsigned pkbf(float a, float b) {
  float2 t; t.x = a; t.y = b;
  __hip_bfloat162 h = __float22bfloat162_rn(t);
  union { __hip_bfloat162 h; unsigned u; } cv;
  cv.h = h;
  return cv.u;
}

// sum across each 16-lane group via DPP row_shr; lane 15 of group holds total.
__device__ __forceinline__ float rowsum16_dpp(float v) {
  union { float f; int i; } x, t;
  x.f = v;
  t.i = __builtin_amdgcn_update_dpp(0, x.i, 0x111, 0xf, 0xf, true); x.f += t.f;
  t.i = __builtin_amdgcn_update_dpp(0, x.i, 0x112, 0xf, 0xf, true); x.f += t.f;
  t.i = __builtin_amdgcn_update_dpp(0, x.i, 0x114, 0xf, 0xf, true); x.f += t.f;
  t.i = __builtin_amdgcn_update_dpp(0, x.i, 0x118, 0xf, 0xf, true); x.f += t.f;
  return x.f;
}

// ---------------- pre-convert f32 -> bf16 ----------------
__global__ __launch_bounds__(256) void cvt_kernel(
    const float* __restrict__ X, const float* __restrict__ Y,
    unsigned short* __restrict__ Xb, unsigned short* __restrict__ Yb) {
  const int groups_per_arr = NN * DD / 8;
  int g = blockIdx.x * 256 + threadIdx.x;
  const float* src;
  unsigned short* dst;
  if (g < groups_per_arr) { src = X; dst = Xb; }
  else { src = Y; dst = Yb; g -= groups_per_arr; }
  float4 a = ((const float4*)src)[(size_t)g * 2];
  float4 b = ((const float4*)src)[(size_t)g * 2 + 1];
  uint4 p = { pkbf(a.x, a.y), pkbf(a.z, a.w), pkbf(b.x, b.y), pkbf(b.z, b.w) };
  ((uint4*)dst)[g] = p;
}

// ---------------- main fused GEMM + softmax-stats (N-walk) ----------------
// 256x256 tile, 8 waves (2Mx4N, wave=128x64), BK=64, 2x64KB double-buffer,
// R8 read-ahead schedule. NEW: block walks JW=4 bcol tiles -> one continuous
// 16-step pipeline; per-j epilogue overlaps the in-flight stage of the next
// tile; rowacc kept in registers across j (1 rowsum atomic pass per block).
__global__ __launch_bounds__(THREADS, 2) void clip_gemm(
    const unsigned short* __restrict__ Xb, const unsigned short* __restrict__ Yb,
    float* __restrict__ rowsum, float* __restrict__ colsum,
    float* __restrict__ diagsum) {
  __shared__ __align__(16) unsigned char sm[2 * 65536];  // [buf][A:32K|B:32K]

  const int tid = threadIdx.x;
  const int bid = blockIdx.x;
  // 1024 blocks: xcd (3b) | cg (4b) | browsub (3b). Concurrent ~32 blocks/XCD
  // span 8 brows x 4 cgs -> X slice 1MB + Y slice 2MB, L2-resident.
  const int xcd = bid & 7;
  const int t0 = bid >> 3;           // 0..127
  const int browsub = t0 & 7;
  const int cg = t0 >> 3;            // 0..15 column group (JW tiles each)
  const int brow = xcd * 8 + browsub;    // 0..63
  const int bcol0 = cg * JW;             // first bcol tile of the walk

  const unsigned short* xb = Xb + (size_t)brow * BM * DD;
  const unsigned short* ybg = Yb + (size_t)bcol0 * BN * DD;

  const int wid = tid >> 6, lane = tid & 63;
  const int wm = wid >> 2, wn = wid & 3;   // wave = rows [wm*128,+128) x cols [wn*64,+64)
  const int lm = lane & 15, lk = lane >> 4;

  // staging slots: per array 2048 x 16B ([256 rows][8 subslots]); 4/thread.
  // LDS slot (row, sl) holds source subslot g = sl ^ (row&7)  (involution).
  int sg[4], sd[4];
#pragma unroll
  for (int p = 0; p < 4; ++p) {
    const int s = p * 512 + tid;
    const int row = s >> 3;
    const int g = (s & 7) ^ (row & 7);
    sg[p] = row * DD + g * 8;
    sd[p] = s * 16;
  }

  // read-side swizzled subslot bytes for kh=0/1 (0-conflict, proven R7/R8)
  const int sl0 = ((lk ^ (lm & 7)) << 4);
  const int sl1 = (((4 | lk) ^ (lm & 7)) << 4);

  f32x4 acc[8][4] = {};
  float rowacc[8][4];
#pragma unroll
  for (int m = 0; m < 8; ++m)
#pragma unroll
    for (int r = 0; r < 4; ++r) rowacc[m][r] = 0.f;
  float dsum = 0.f;
  const float negC = -(SHIFT_C * LOG2E);

#define GLOAD(sn, p)                                                           \
  {                                                                            \
    const int tn_ = (sn) & 3, jn_ = (sn) >> 2;                                 \
    __builtin_amdgcn_global_load_lds(                                          \
        (const __attribute__((address_space(1))) unsigned*)(xb + sg[p] + tn_ * BK), \
        (__attribute__((address_space(3))) unsigned*)(sm + ((sn) & 1) * 65536 + sd[p]), \
        16, 0, 0);                                                             \
    __builtin_amdgcn_global_load_lds(                                          \
        (const __attribute__((address_space(1))) unsigned*)(ybg + (size_t)jn_ * (BN * DD) + sg[p] + tn_ * BK), \
        (__attribute__((address_space(3))) unsigned*)(sm + ((sn) & 1) * 65536 + 32768 + sd[p]), \
        16, 0, 0);                                                             \
  }

#define RDA(buf, mi, sl) (*(const bf16x8*)((buf) + (wm * 128 + (mi) * 16 + lm) * 128 + (sl)))
#define RDB(buf, nf, sl) (*(const bf16x8*)((buf) + (wn * 64 + (nf) * 16 + lm) * 128 + (sl)))

#define MFMA8(x0, x1, bs, m0)                                                  \
  {                                                                            \
    _Pragma("unroll")                                                          \
    for (int nf = 0; nf < 4; ++nf)                                             \
      acc[m0][nf] = __builtin_amdgcn_mfma_f32_16x16x32_bf16(x0, bs[nf], acc[m0][nf], 0, 0, 0); \
    _Pragma("unroll")                                                          \
    for (int nf = 0; nf < 4; ++nf)                                             \
      acc[(m0) + 1][nf] = __builtin_amdgcn_mfma_f32_16x16x32_bf16(x1, bs[nf], acc[(m0) + 1][nf], 0, 0, 0); \
  }

  // prologue: stage step 0
  GLOAD(0, 0); GLOAD(0, 1); GLOAD(0, 2); GLOAD(0, 3);

#pragma unroll
  for (int s = 0; s < NS; ++s) {
    const int j = s >> 2;        // bcol tile index in the walk
    const int cur = s & 1;
    __syncthreads();  // vmcnt(0)+lgkmcnt(0)+barrier: buf[cur] fully staged
    const unsigned char* bA = sm + cur * 65536;
    const unsigned char* bB = bA + 32768;
    bf16x8 aC0, aC1, aN0, aN1, b0[4], b1[4];
    aC0 = RDA(bA, 0, sl0); aC1 = RDA(bA, 1, sl0);
#pragma unroll
    for (int nf = 0; nf < 4; ++nf) b0[nf] = RDB(bB, nf, sl0);
    if (s < NS - 1) GLOAD(s + 1, 0);
    aN0 = RDA(bA, 2, sl0); aN1 = RDA(bA, 3, sl0);
    MFMA8(aC0, aC1, b0, 0);
    if (s < NS - 1) GLOAD(s + 1, 1);
    aC0 = RDA(bA, 4, sl0); aC1 = RDA(bA, 5, sl0);
    MFMA8(aN0, aN1, b0, 2);
    if (s < NS - 1) GLOAD(s + 1, 2);
    aN0 = RDA(bA, 6, sl0); aN1 = RDA(bA, 7, sl0);
    MFMA8(aC0, aC1, b0, 4);
    if (s < NS - 1) GLOAD(s + 1, 3);
    aC0 = RDA(bA, 0, sl1); aC1 = RDA(bA, 1, sl1);
#pragma unroll
    for (int nf = 0; nf < 4; ++nf) b1[nf] = RDB(bB, nf, sl1);
    MFMA8(aN0, aN1, b0, 6);
    aN0 = RDA(bA, 2, sl1); aN1 = RDA(bA, 3, sl1);
    MFMA8(aC0, aC1, b1, 0);
    aC0 = RDA(bA, 4, sl1); aC1 = RDA(bA, 5, sl1);
    MFMA8(aN0, aN1, b1, 2);
    aN0 = RDA(bA, 6, sl1); aN1 = RDA(bA, 7, sl1);
    MFMA8(aC0, aC1, b1, 4);
    MFMA8(aN0, aN1, b1, 6);

    if ((s & 3) == 3) {
      // ---- per-j epilogue: runs while stage of s+1 is in flight ----
      const int bcol = bcol0 + j;
      float colacc[4] = {0.f, 0.f, 0.f, 0.f};
#pragma unroll
      for (int m = 0; m < 8; ++m)
#pragma unroll
        for (int n = 0; n < 4; ++n)
#pragma unroll
          for (int r = 0; r < 4; ++r) {
            float e = EXP2F(__builtin_fmaf(acc[m][n][r], LOG2E, negC));
            rowacc[m][r] += e;
            colacc[n] += e;
          }
      // diagonal logits of this tile
      if (brow == bcol && (wn >> 1) == wm) {
#pragma unroll
        for (int m = 0; m < 8; ++m)
#pragma unroll
          for (int n = 0; n < 4; ++n)
#pragma unroll
            for (int r = 0; r < 4; ++r) {
              const int rr = wm * 128 + m * 16 + lk * 4 + r;
              const int cc = wn * 64 + n * 16 + lm;
              if (rr == cc) dsum += acc[m][n][r];
            }
      }
      // col sums: reduce across lk (lane>>4), atomic per column
#pragma unroll
      for (int n = 0; n < 4; ++n) {
        float v = colacc[n];
        v += __shfl_xor(v, 16);
        v += __shfl_xor(v, 32);
        if (lk == 0)
          atomicAdd(&colsum[bcol * BN + wn * 64 + n * 16 + lm], v);
      }
      // reset accumulators for next tile
      const f32x4 z4 = {0.f, 0.f, 0.f, 0.f};
#pragma unroll
      for (int m = 0; m < 8; ++m)
#pragma unroll
        for (int n = 0; n < 4; ++n) acc[m][n] = z4;
    }
  }
#undef GLOAD
#undef RDA
#undef RDB
#undef MFMA8

  // ---- block-end: diagonal + row sums (accumulated over all JW tiles) ----
  {
    float d = dsum;
    d += __shfl_xor(d, 1);
    d += __shfl_xor(d, 2);
    d += __shfl_xor(d, 4);
    d += __shfl_xor(d, 8);
    d += __shfl_xor(d, 16);
    d += __shfl_xor(d, 32);
    if (lane == 0 && d != 0.f) atomicAdd(diagsum, d);
  }
#pragma unroll
  for (int m = 0; m < 8; ++m)
#pragma unroll
    for (int r = 0; r < 4; ++r) {
      float v = rowsum16_dpp(rowacc[m][r]);
      if (lm == 15)
        atomicAdd(&rowsum[brow * BM + wm * 128 + m * 16 + lk * 4 + r], v);
    }
}

// ---------------- fallback (reg-staging, no ws bf16 buffers) ----------------
__global__ __launch_bounds__(256) void clip_main_fb(
    const float* __restrict__ X, const float* __restrict__ Y,
    float* __restrict__ rowsum, float* __restrict__ colsum,
    float* __restrict__ diagsum) {
  __shared__ __align__(16) unsigned char smem[2 * 128 * 64 * 2];
  unsigned char* smA = smem;
  unsigned char* smB = smem + 128 * 64 * 2;

  const int tid = threadIdx.x;
  const int bid = blockIdx.x;
  const int swz = (bid & 7) * 2048 + (bid >> 3);
  const int brow = swz >> 7;
  const int bcol = swz & 127;

  const float* xb = X + (size_t)brow * 128 * DD;
  const float* yb = Y + (size_t)bcol * 128 * DD;

  const int wid = tid >> 6, lane = tid & 63;
  const int wm = wid >> 1, wn = wid & 1;
  const int lm = lane & 15, lk = lane >> 4;

  f32x4 acc[4][4] = {};

  for (int ks = 0; ks < 4; ++ks) {
    const int kbase = ks * 64;
    if (ks) __syncthreads();
#pragma unroll
    for (int i = 0; i < 4; ++i) {
      const int c = tid + i * 256;
      const int row = c >> 3, slot = c & 7;
      const int boff = row * 128 + ((slot << 4) ^ ((row & 7) << 4));
      const float* ga = xb + row * DD + kbase + (slot << 3);
      float4 a0 = *(const float4*)ga;
      float4 a1 = *(const float4*)(ga + 4);
      uint4 pa = { pkbf(a0.x, a0.y), pkbf(a0.z, a0.w),
                   pkbf(a1.x, a1.y), pkbf(a1.z, a1.w) };
      *(uint4*)(smA + boff) = pa;
      const float* gb = yb + row * DD + kbase + (slot << 3);
      float4 b0 = *(const float4*)gb;
      float4 b1 = *(const float4*)(gb + 4);
      uint4 pb = { pkbf(b0.x, b0.y), pkbf(b0.z, b0.w),
                   pkbf(b1.x, b1.y), pkbf(b1.z, b1.w) };
      *(uint4*)(smB + boff) = pb;
    }
    __syncthreads();

#pragma unroll
    for (int kk = 0; kk < 2; ++kk) {
      const int kboff = kk * 64 + lk * 16;
      bf16x8 a[4], b[4];
#pragma unroll
      for (int m = 0; m < 4; ++m) {
        const int row = wm * 64 + m * 16 + lm;
        a[m] = *(const bf16x8*)(smA + row * 128 + (kboff ^ ((row & 7) << 4)));
      }
#pragma unroll
      for (int n = 0; n < 4; ++n) {
        const int row = wn * 64 + n * 16 + lm;
        b[n] = *(const bf16x8*)(smB + row * 128 + (kboff ^ ((row & 7) << 4)));
      }
#pragma unroll
      for (int m = 0; m < 4; ++m)
#pragma unroll
        for (int n = 0; n < 4; ++n)
          acc[m][n] = __builtin_amdgcn_mfma_f32_16x16x32_bf16(a[m], b[n], acc[m][n], 0, 0, 0);
    }
  }

  float rowacc[4][4];
  float colacc[4];
#pragma unroll
  for (int m = 0; m < 4; ++m)
#pragma unroll
    for (int r = 0; r < 4; ++r) rowacc[m][r] = 0.f;
#pragma unroll
  for (int n = 0; n < 4; ++n) colacc[n] = 0.f;

  const float negC = -(SHIFT_C * LOG2E);
#pragma unroll
  for (int m = 0; m < 4; ++m)
#pragma unroll
    for (int n = 0; n < 4; ++n)
#pragma unroll
      for (int r = 0; r < 4; ++r) {
        float e = EXP2F(__builtin_fmaf(acc[m][n][r], LOG2E, negC));
        rowacc[m][r] += e;
        colacc[n] += e;
      }

  if (brow == bcol && wm == wn) {
    float dsum = 0.f;
#pragma unroll
    for (int m = 0; m < 4; ++m)
#pragma unroll
      for (int n = 0; n < 4; ++n)
#pragma unroll
        for (int r = 0; r < 4; ++r) {
          const int rr = m * 16 + lk * 4 + r;
          const int cc = n * 16 + lm;
          if (rr == cc) dsum += acc[m][n][r];
        }
    dsum += __shfl_xor(dsum, 1);
    dsum += __shfl_xor(dsum, 2);
    dsum += __shfl_xor(dsum, 4);
    dsum += __shfl_xor(dsum, 8);
    dsum += __shfl_xor(dsum, 16);
    dsum += __shfl_xor(dsum, 32);
    if (lane == 0) atomicAdd(diagsum, dsum);
  }

#pragma unroll
  for (int m = 0; m < 4; ++m)
#pragma unroll
    for (int r = 0; r < 4; ++r) {
      float v = rowsum16_dpp(rowacc[m][r]);
      if (lm == 15)
        atomicAdd(&rowsum[brow * 128 + wm * 64 + m * 16 + lk * 4 + r], v);
    }
#pragma unroll
  for (int n = 0; n < 4; ++n) {
    float v = colacc[n];
    v += __shfl_xor(v, 16);
    v += __shfl_xor(v, 32);
    if (lk == 0)
      atomicAdd(&colsum[bcol * 128 + wn * 64 + n * 16 + lm], v);
  }
}

// ---------------- final reduction: 64 blocks + 1-thread finisher ----------------
__global__ __launch_bounds__(256) void clip_stats(
    const float* __restrict__ rowsum, const float* __restrict__ colsum,
    float* __restrict__ partial) {
  __shared__ float sdata[4];
  const int i = blockIdx.x * 256 + threadIdx.x;
  float s = logf(rowsum[i]) + logf(colsum[i]);
  s += __shfl_xor(s, 1);
  s += __shfl_xor(s, 2);
  s += __shfl_xor(s, 4);
  s += __shfl_xor(s, 8);
  s += __shfl_xor(s, 16);
  s += __shfl_xor(s, 32);
  const int lane = threadIdx.x & 63, wv = threadIdx.x >> 6;
  if (lane == 0) sdata[wv] = s;
  __syncthreads();
  if (threadIdx.x == 0)
    atomicAdd(partial, sdata[0] + sdata[1] + sdata[2] + sdata[3]);
}

__global__ void clip_out(const float* __restrict__ partial,
                         const float* __restrict__ diagsum,
                         float* __restrict__ out) {
  if (threadIdx.x == 0)
    out[0] = (float)((double)SHIFT_C + (double)partial[0] * 0.5 / (double)NN
                     - (double)diagsum[0] / (double)NN);
}

extern "C" void kernel_launch(void* const* d_in, const int* in_sizes, int n_in,
                              void* d_out, int out_size, void* d_ws, size_t ws_size,
                              hipStream_t stream) {
  const float* X = (const float*)d_in[0];
  const float* Y = (const float*)d_in[1];

  const size_t bf16_bytes = (size_t)2 * NN * DD * sizeof(unsigned short);  // 16 MB
  const size_t stats_bytes = (size_t)(2 * NN + 2) * sizeof(float);

  if (ws_size >= bf16_bytes + stats_bytes) {
    unsigned short* Xb = (unsigned short*)d_ws;
    unsigned short* Yb = Xb + (size_t)NN * DD;
    float* rowsum = (float*)((unsigned char*)d_ws + bf16_bytes);
    float* colsum = rowsum + NN;
    float* diagsum = colsum + NN;
    float* partial = diagsum + 1;

    hipMemsetAsync(rowsum, 0, stats_bytes, stream);
    cvt_kernel<<<dim3(2 * NN * DD / 8 / 256), dim3(256), 0, stream>>>(X, Y, Xb, Yb);
    clip_gemm<<<dim3((NN / BM) * (NN / (BN * JW))), dim3(THREADS), 0, stream>>>(
        Xb, Yb, rowsum, colsum, diagsum);
    clip_stats<<<dim3(NN / 256), dim3(256), 0, stream>>>(rowsum, colsum, partial);
    clip_out<<<dim3(1), dim3(64), 0, stream>>>(partial, diagsum, (float*)d_out);
  } else {
    float* rowsum = (float*)d_ws;
    float* colsum = rowsum + NN;
    float* diagsum = colsum + NN;
    float* partial = diagsum + 1;
    hipMemsetAsync(d_ws, 0, stats_bytes, stream);
    clip_main_fb<<<dim3((NN / 128) * (NN / 128)), dim3(256), 0, stream>>>(
        X, Y, rowsum, colsum, diagsum);
    clip_stats<<<dim3(NN / 256), dim3(256), 0, stream>>>(rowsum, colsum, partial);
    clip_out<<<dim3(1), dim3(64), 0, stream>>>(partial, diagsum, (float*)d_out);
  }
}

// Round 10
// 239.840 us; speedup vs baseline: 2.3469x; 2.3469x over previous
//
#include <hip/hip_runtime.h>
#include <hip/hip_bf16.h>

#define NN 16384
#define DD 256
#define BM 128
#define BN 128
#define BK 64
#define NKT 4                  // 256 / 64 K-tiles
#define THREADS 256
#define SHIFT_C 64.0f
#define LOG2E 1.4426950408889634f

typedef __attribute__((ext_vector_type(4))) float f32x4;
typedef __attribute__((ext_vector_type(8))) short bf16x8;

#if __has_builtin(__builtin_amdgcn_exp2f)
#define EXP2F(x) __builtin_amdgcn_exp2f(x)
#else
#define EXP2F(x) exp2f(x)
#endif

__device__ __forceinline__ unsigned pkbf(float a, float b) {
  float2 t; t.x = a; t.y = b;
  __hip_bfloat162 h = __float22bfloat162_rn(t);
  union { __hip_bfloat162 h; unsigned u; } cv;
  cv.h = h;
  return cv.u;
}

// sum across each 16-lane group via DPP row_shr; lane 15 of group holds total.
__device__ __forceinline__ float rowsum16_dpp(float v) {
  union { float f; int i; } x, t;
  x.f = v;
  t.i = __builtin_amdgcn_update_dpp(0, x.i, 0x111, 0xf, 0xf, true); x.f += t.f;
  t.i = __builtin_amdgcn_update_dpp(0, x.i, 0x112, 0xf, 0xf, true); x.f += t.f;
  t.i = __builtin_amdgcn_update_dpp(0, x.i, 0x114, 0xf, 0xf, true); x.f += t.f;
  t.i = __builtin_amdgcn_update_dpp(0, x.i, 0x118, 0xf, 0xf, true); x.f += t.f;
  return x.f;
}

// ---------------- pre-convert f32 -> bf16 ----------------
__global__ __launch_bounds__(256) void cvt_kernel(
    const float* __restrict__ X, const float* __restrict__ Y,
    unsigned short* __restrict__ Xb, unsigned short* __restrict__ Yb) {
  const int groups_per_arr = NN * DD / 8;
  int g = blockIdx.x * 256 + threadIdx.x;
  const float* src;
  unsigned short* dst;
  if (g < groups_per_arr) { src = X; dst = Xb; }
  else { src = Y; dst = Yb; g -= groups_per_arr; }
  float4 a = ((const float4*)src)[(size_t)g * 2];
  float4 b = ((const float4*)src)[(size_t)g * 2 + 1];
  uint4 p = { pkbf(a.x, a.y), pkbf(a.z, a.w), pkbf(b.x, b.y), pkbf(b.z, b.w) };
  ((uint4*)dst)[g] = p;
}

// ---------------- main fused GEMM + softmax-stats ----------------
// R8's read-ahead schedule at 128x128 geometry: 4 waves (2Mx2N, wave=64x64),
// BK=64, 2x32KB LDS double-buffer => 64KB/block => 2 BLOCKS/CU co-resident
// (16 waves/CU). One block's sync/stage stalls hide under the other's MFMA.
// Epilogue at block end only (R9's in-loop epilogue caused scratch spill).
__global__ __launch_bounds__(THREADS, 2) void clip_gemm(
    const unsigned short* __restrict__ Xb, const unsigned short* __restrict__ Yb,
    float* __restrict__ rowsum, float* __restrict__ colsum,
    float* __restrict__ diagsum) {
  __shared__ __align__(16) unsigned char sm[2 * 32768];  // [buf][A:16K|B:16K]

  const int tid = threadIdx.x;
  const int bid = blockIdx.x;
  // XCD swizzle: 16384 blocks; each XCD owns brows [xcd*16, +16).
  // Concurrent ~64 blocks/XCD span 16 brows x 4 bcols -> X 1MB + Y 256KB in L2.
  const int xcd = bid & 7;
  const int t0 = bid >> 3;            // 0..2047
  const int brow = xcd * 16 + (t0 & 15);  // 0..127
  const int bcol = t0 >> 4;               // 0..127

  const unsigned short* xb = Xb + (size_t)brow * BM * DD;
  const unsigned short* yb = Yb + (size_t)bcol * BN * DD;

  const int wid = tid >> 6, lane = tid & 63;
  const int wm = wid >> 1, wn = wid & 1;   // wave = rows [wm*64,+64) x cols [wn*64,+64)
  const int lm = lane & 15, lk = lane >> 4;

  // staging: per array 1024 slots of 16B ([128 rows][8 subslots]); 4/thread.
  // LDS slot (row, sl) holds source subslot g = sl ^ (row&7)  (involution).
  int sg[4], sd[4];
#pragma unroll
  for (int p = 0; p < 4; ++p) {
    const int s = p * 256 + tid;
    const int row = s >> 3;
    const int g = (s & 7) ^ (row & 7);
    sg[p] = row * DD + g * 8;
    sd[p] = s * 16;
  }

  // read-side swizzled subslot bytes for kh=0/1 (0-conflict, proven R7/R8)
  const int sl0 = ((lk ^ (lm & 7)) << 4);
  const int sl1 = (((4 | lk) ^ (lm & 7)) << 4);

  f32x4 acc[4][4] = {};

#define GLOAD(t1, p)                                                           \
  {                                                                            \
    __builtin_amdgcn_global_load_lds(                                          \
        (const __attribute__((address_space(1))) unsigned*)(xb + sg[p] + (t1) * BK), \
        (__attribute__((address_space(3))) unsigned*)(sm + ((t1) & 1) * 32768 + sd[p]), \
        16, 0, 0);                                                             \
    __builtin_amdgcn_global_load_lds(                                          \
        (const __attribute__((address_space(1))) unsigned*)(yb + sg[p] + (t1) * BK), \
        (__attribute__((address_space(3))) unsigned*)(sm + ((t1) & 1) * 32768 + 16384 + sd[p]), \
        16, 0, 0);                                                             \
  }

#define RDA(buf, mi, sl) (*(const bf16x8*)((buf) + (wm * 64 + (mi) * 16 + lm) * 128 + (sl)))
#define RDB(buf, nf, sl) (*(const bf16x8*)((buf) + (wn * 64 + (nf) * 16 + lm) * 128 + (sl)))

#define MFMA8(x0, x1, bs, m0)                                                  \
  {                                                                            \
    _Pragma("unroll")                                                          \
    for (int nf = 0; nf < 4; ++nf)                                             \
      acc[m0][nf] = __builtin_amdgcn_mfma_f32_16x16x32_bf16(x0, bs[nf], acc[m0][nf], 0, 0, 0); \
    _Pragma("unroll")                                                          \
    for (int nf = 0; nf < 4; ++nf)                                             \
      acc[(m0) + 1][nf] = __builtin_amdgcn_mfma_f32_16x16x32_bf16(x1, bs[nf], acc[(m0) + 1][nf], 0, 0, 0); \
  }

  // prologue: stage tile 0
  GLOAD(0, 0); GLOAD(0, 1); GLOAD(0, 2); GLOAD(0, 3);

#pragma unroll
  for (int t = 0; t < NKT; ++t) {
    const int cur = t & 1;
    __syncthreads();  // vmcnt(0)+lgkmcnt(0)+barrier: buf[cur] fully staged
    const unsigned char* bA = sm + cur * 32768;
    const unsigned char* bB = bA + 16384;
    bf16x8 aC0, aC1, aN0, aN1, b0[4], b1[4];
    // initial reads: kh0 m0/m1 + B(kh0)
    aC0 = RDA(bA, 0, sl0); aC1 = RDA(bA, 1, sl0);
#pragma unroll
    for (int nf = 0; nf < 4; ++nf) b0[nf] = RDB(bB, nf, sl0);
    // p0
    if (t < NKT - 1) GLOAD(t + 1, 0);
    aN0 = RDA(bA, 2, sl0); aN1 = RDA(bA, 3, sl0);
    MFMA8(aC0, aC1, b0, 0);
    // p1: prefetch kh1 m0/m1 + B(kh1)
    if (t < NKT - 1) GLOAD(t + 1, 1);
    aC0 = RDA(bA, 0, sl1); aC1 = RDA(bA, 1, sl1);
#pragma unroll
    for (int nf = 0; nf < 4; ++nf) b1[nf] = RDB(bB, nf, sl1);
    MFMA8(aN0, aN1, b0, 2);
    // p2
    if (t < NKT - 1) GLOAD(t + 1, 2);
    aN0 = RDA(bA, 2, sl1); aN1 = RDA(bA, 3, sl1);
    MFMA8(aC0, aC1, b1, 0);   // kh1 accumulates into same acc
    // p3
    if (t < NKT - 1) GLOAD(t + 1, 3);
    MFMA8(aN0, aN1, b1, 2);
  }
#undef GLOAD
#undef RDA
#undef RDB
#undef MFMA8

  // ---- fused softmax-statistics epilogue (block end only) ----
  float rowacc[4][4];
  float colacc[4];
#pragma unroll
  for (int m = 0; m < 4; ++m)
#pragma unroll
    for (int r = 0; r < 4; ++r) rowacc[m][r] = 0.f;
#pragma unroll
  for (int n = 0; n < 4; ++n) colacc[n] = 0.f;

  const float negC = -(SHIFT_C * LOG2E);
#pragma unroll
  for (int m = 0; m < 4; ++m)
#pragma unroll
    for (int n = 0; n < 4; ++n)
#pragma unroll
      for (int r = 0; r < 4; ++r) {
        float e = EXP2F(__builtin_fmaf(acc[m][n][r], LOG2E, negC));
        rowacc[m][r] += e;
        colacc[n] += e;
      }

  // diagonal logits (diagonal blocks, diagonal waves)
  if (brow == bcol && wm == wn) {
    float dsum = 0.f;
#pragma unroll
    for (int m = 0; m < 4; ++m)
#pragma unroll
      for (int n = 0; n < 4; ++n)
#pragma unroll
        for (int r = 0; r < 4; ++r) {
          const int rr = m * 16 + lk * 4 + r;
          const int cc = n * 16 + lm;
          if (rr == cc) dsum += acc[m][n][r];
        }
    dsum += __shfl_xor(dsum, 1);
    dsum += __shfl_xor(dsum, 2);
    dsum += __shfl_xor(dsum, 4);
    dsum += __shfl_xor(dsum, 8);
    dsum += __shfl_xor(dsum, 16);
    dsum += __shfl_xor(dsum, 32);
    if (lane == 0) atomicAdd(diagsum, dsum);
  }

  // row sums via DPP (VALU); lane lm==15 holds the 16-lane total
#pragma unroll
  for (int m = 0; m < 4; ++m)
#pragma unroll
    for (int r = 0; r < 4; ++r) {
      float v = rowsum16_dpp(rowacc[m][r]);
      if (lm == 15)
        atomicAdd(&rowsum[brow * BM + wm * 64 + m * 16 + lk * 4 + r], v);
    }
  // col sums: reduce across lk
#pragma unroll
  for (int n = 0; n < 4; ++n) {
    float v = colacc[n];
    v += __shfl_xor(v, 16);
    v += __shfl_xor(v, 32);
    if (lk == 0)
      atomicAdd(&colsum[bcol * BN + wn * 64 + n * 16 + lm], v);
  }
}

// ---------------- fallback (reg-staging, no ws bf16 buffers) ----------------
__global__ __launch_bounds__(256) void clip_main_fb(
    const float* __restrict__ X, const float* __restrict__ Y,
    float* __restrict__ rowsum, float* __restrict__ colsum,
    float* __restrict__ diagsum) {
  __shared__ __align__(16) unsigned char smem[2 * 128 * 64 * 2];
  unsigned char* smA = smem;
  unsigned char* smB = smem + 128 * 64 * 2;

  const int tid = threadIdx.x;
  const int bid = blockIdx.x;
  const int swz = (bid & 7) * 2048 + (bid >> 3);
  const int brow = swz >> 7;
  const int bcol = swz & 127;

  const float* xb = X + (size_t)brow * 128 * DD;
  const float* yb = Y + (size_t)bcol * 128 * DD;

  const int wid = tid >> 6, lane = tid & 63;
  const int wm = wid >> 1, wn = wid & 1;
  const int lm = lane & 15, lk = lane >> 4;

  f32x4 acc[4][4] = {};

  for (int ks = 0; ks < 4; ++ks) {
    const int kbase = ks * 64;
    if (ks) __syncthreads();
#pragma unroll
    for (int i = 0; i < 4; ++i) {
      const int c = tid + i * 256;
      const int row = c >> 3, slot = c & 7;
      const int boff = row * 128 + ((slot << 4) ^ ((row & 7) << 4));
      const float* ga = xb + row * DD + kbase + (slot << 3);
      float4 a0 = *(const float4*)ga;
      float4 a1 = *(const float4*)(ga + 4);
      uint4 pa = { pkbf(a0.x, a0.y), pkbf(a0.z, a0.w),
                   pkbf(a1.x, a1.y), pkbf(a1.z, a1.w) };
      *(uint4*)(smA + boff) = pa;
      const float* gb = yb + row * DD + kbase + (slot << 3);
      float4 b0 = *(const float4*)gb;
      float4 b1 = *(const float4*)(gb + 4);
      uint4 pb = { pkbf(b0.x, b0.y), pkbf(b0.z, b0.w),
                   pkbf(b1.x, b1.y), pkbf(b1.z, b1.w) };
      *(uint4*)(smB + boff) = pb;
    }
    __syncthreads();

#pragma unroll
    for (int kk = 0; kk < 2; ++kk) {
      const int kboff = kk * 64 + lk * 16;
      bf16x8 a[4], b[4];
#pragma unroll
      for (int m = 0; m < 4; ++m) {
        const int row = wm * 64 + m * 16 + lm;
        a[m] = *(const bf16x8*)(smA + row * 128 + (kboff ^ ((row & 7) << 4)));
      }
#pragma unroll
      for (int n = 0; n < 4; ++n) {
        const int row = wn * 64 + n * 16 + lm;
        b[n] = *(const bf16x8*)(smB + row * 128 + (kboff ^ ((row & 7) << 4)));
      }
#pragma unroll
      for (int m = 0; m < 4; ++m)
#pragma unroll
        for (int n = 0; n < 4; ++n)
          acc[m][n] = __builtin_amdgcn_mfma_f32_16x16x32_bf16(a[m], b[n], acc[m][n], 0, 0, 0);
    }
  }

  float rowacc[4][4];
  float colacc[4];
#pragma unroll
  for (int m = 0; m < 4; ++m)
#pragma unroll
    for (int r = 0; r < 4; ++r) rowacc[m][r] = 0.f;
#pragma unroll
  for (int n = 0; n < 4; ++n) colacc[n] = 0.f;

  const float negC = -(SHIFT_C * LOG2E);
#pragma unroll
  for (int m = 0; m < 4; ++m)
#pragma unroll
    for (int n = 0; n < 4; ++n)
#pragma unroll
      for (int r = 0; r < 4; ++r) {
        float e = EXP2F(__builtin_fmaf(acc[m][n][r], LOG2E, negC));
        rowacc[m][r] += e;
        colacc[n] += e;
      }

  if (brow == bcol && wm == wn) {
    float dsum = 0.f;
#pragma unroll
    for (int m = 0; m < 4; ++m)
#pragma unroll
      for (int n = 0; n < 4; ++n)
#pragma unroll
        for (int r = 0; r < 4; ++r) {
          const int rr = m * 16 + lk * 4 + r;
          const int cc = n * 16 + lm;
          if (rr == cc) dsum += acc[m][n][r];
        }
    dsum += __shfl_xor(dsum, 1);
    dsum += __shfl_xor(dsum, 2);
    dsum += __shfl_xor(dsum, 4);
    dsum += __shfl_xor(dsum, 8);
    dsum += __shfl_xor(dsum, 16);
    dsum += __shfl_xor(dsum, 32);
    if (lane == 0) atomicAdd(diagsum, dsum);
  }

#pragma unroll
  for (int m = 0; m < 4; ++m)
#pragma unroll
    for (int r = 0; r < 4; ++r) {
      float v = rowsum16_dpp(rowacc[m][r]);
      if (lm == 15)
        atomicAdd(&rowsum[brow * 128 + wm * 64 + m * 16 + lk * 4 + r], v);
    }
#pragma unroll
  for (int n = 0; n < 4; ++n) {
    float v = colacc[n];
    v += __shfl_xor(v, 16);
    v += __shfl_xor(v, 32);
    if (lk == 0)
      atomicAdd(&colsum[bcol * 128 + wn * 64 + n * 16 + lm], v);
  }
}

// ---------------- final reduction: parallel stats + tiny finisher ----------------
__global__ __launch_bounds__(256) void clip_stats(
    const float* __restrict__ rowsum, const float* __restrict__ colsum,
    float* __restrict__ partial) {
  __shared__ float sdata[4];
  const int i = blockIdx.x * 256 + threadIdx.x;
  float s = logf(rowsum[i]) + logf(colsum[i]);
  s += __shfl_xor(s, 1);
  s += __shfl_xor(s, 2);
  s += __shfl_xor(s, 4);
  s += __shfl_xor(s, 8);
  s += __shfl_xor(s, 16);
  s += __shfl_xor(s, 32);
  const int lane = threadIdx.x & 63, wv = threadIdx.x >> 6;
  if (lane == 0) sdata[wv] = s;
  __syncthreads();
  if (threadIdx.x == 0)
    atomicAdd(partial, sdata[0] + sdata[1] + sdata[2] + sdata[3]);
}

__global__ void clip_out(const float* __restrict__ partial,
                         const float* __restrict__ diagsum,
                         float* __restrict__ out) {
  if (threadIdx.x == 0)
    out[0] = (float)((double)SHIFT_C + (double)partial[0] * 0.5 / (double)NN
                     - (double)diagsum[0] / (double)NN);
}

extern "C" void kernel_launch(void* const* d_in, const int* in_sizes, int n_in,
                              void* d_out, int out_size, void* d_ws, size_t ws_size,
                              hipStream_t stream) {
  const float* X = (const float*)d_in[0];
  const float* Y = (const float*)d_in[1];

  const size_t bf16_bytes = (size_t)2 * NN * DD * sizeof(unsigned short);  // 16 MB
  const size_t stats_bytes = (size_t)(2 * NN + 2) * sizeof(float);

  if (ws_size >= bf16_bytes + stats_bytes) {
    unsigned short* Xb = (unsigned short*)d_ws;
    unsigned short* Yb = Xb + (size_t)NN * DD;
    float* rowsum = (float*)((unsigned char*)d_ws + bf16_bytes);
    float* colsum = rowsum + NN;
    float* diagsum = colsum + NN;
    float* partial = diagsum + 1;

    hipMemsetAsync(rowsum, 0, stats_bytes, stream);
    cvt_kernel<<<dim3(2 * NN * DD / 8 / 256), dim3(256), 0, stream>>>(X, Y, Xb, Yb);
    clip_gemm<<<dim3((NN / BM) * (NN / BN)), dim3(THREADS), 0, stream>>>(
        Xb, Yb, rowsum, colsum, diagsum);
    clip_stats<<<dim3(NN / 256), dim3(256), 0, stream>>>(rowsum, colsum, partial);
    clip_out<<<dim3(1), dim3(64), 0, stream>>>(partial, diagsum, (float*)d_out);
  } else {
    float* rowsum = (float*)d_ws;
    float* colsum = rowsum + NN;
    float* diagsum = colsum + NN;
    float* partial = diagsum + 1;
    hipMemsetAsync(d_ws, 0, stats_bytes, stream);
    clip_main_fb<<<dim3((NN / 128) * (NN / 128)), dim3(256), 0, stream>>>(
        X, Y, rowsum, colsum, diagsum);
    clip_stats<<<dim3(NN / 256), dim3(256), 0, stream>>>(rowsum, colsum, partial);
    clip_out<<<dim3(1), dim3(64), 0, stream>>>(partial, diagsum, (float*)d_out);
  }
}

// Round 11
// 210.203 us; speedup vs baseline: 2.6778x; 1.1410x over previous
//
#include <hip/hip_runtime.h>
#include <hip/hip_bf16.h>

#define NN 16384
#define DD 256
#define PANEL 256              // A rows per block (resident in LDS)
#define JCOLS 128              // cols per j-tile
#define BKT 64                 // k per t-step
#define NT 4                   // K-steps per j  (NT*BKT == DD)
#define NJ 16                  // j-tiles per block (2048 cols)
#define THREADS 512
#define A_BYTES (PANEL * DD * 2)        // 131072
#define B_BYTES (JCOLS * BKT * 2)       // 16384
#define LDS_TOTAL (A_BYTES + 2 * B_BYTES)  // 163840
#define SHIFT_C 64.0f
#define LOG2E 1.4426950408889634f

typedef __attribute__((ext_vector_type(4))) float f32x4;
typedef __attribute__((ext_vector_type(8))) short bf16x8;

#if __has_builtin(__builtin_amdgcn_exp2f)
#define EXP2F(x) __builtin_amdgcn_exp2f(x)
#else
#define EXP2F(x) exp2f(x)
#endif

__device__ __forceinline__ unsigned pkbf(float a, float b) {
  float2 t; t.x = a; t.y = b;
  __hip_bfloat162 h = __float22bfloat162_rn(t);
  union { __hip_bfloat162 h; unsigned u; } cv;
  cv.h = h;
  return cv.u;
}

// sum across each 16-lane group via DPP row_shr; lane 15 of group holds total.
__device__ __forceinline__ float rowsum16_dpp(float v) {
  union { float f; int i; } x, t;
  x.f = v;
  t.i = __builtin_amdgcn_update_dpp(0, x.i, 0x111, 0xf, 0xf, true); x.f += t.f;
  t.i = __builtin_amdgcn_update_dpp(0, x.i, 0x112, 0xf, 0xf, true); x.f += t.f;
  t.i = __builtin_amdgcn_update_dpp(0, x.i, 0x114, 0xf, 0xf, true); x.f += t.f;
  t.i = __builtin_amdgcn_update_dpp(0, x.i, 0x118, 0xf, 0xf, true); x.f += t.f;
  return x.f;
}

// ---------------- pre-convert f32 -> bf16 ----------------
__global__ __launch_bounds__(256) void cvt_kernel(
    const float* __restrict__ X, const float* __restrict__ Y,
    unsigned short* __restrict__ Xb, unsigned short* __restrict__ Yb) {
  const int groups_per_arr = NN * DD / 8;
  int g = blockIdx.x * 256 + threadIdx.x;
  const float* src;
  unsigned short* dst;
  if (g < groups_per_arr) { src = X; dst = Xb; }
  else { src = Y; dst = Yb; g -= groups_per_arr; }
  float4 a = ((const float4*)src)[(size_t)g * 2];
  float4 b = ((const float4*)src)[(size_t)g * 2 + 1];
  uint4 p = { pkbf(a.x, a.y), pkbf(a.z, a.w), pkbf(b.x, b.y), pkbf(b.z, b.w) };
  ((uint4*)dst)[g] = p;
}

// ---------------- main fused GEMM + softmax-stats (A-resident walk) ----------------
// A panel (256 rows x K=256, 128KB) loaded into LDS ONCE and kept resident.
// Block walks NJ=16 j-tiles (256x128) x NT=4 K-steps = 64-step pipeline.
// Only B staged per step (16KB, 2x dbuf). 8 waves (4m x 2n), wave = 64x64.
// One barrier per step; stage(s+1) issued right after it (full-step runway).
// rowacc in registers across the whole walk; per-j epilogue in a RUNTIME
// j-loop (R9's spill came from full unroll).
__global__ __launch_bounds__(THREADS, 2) void clip_gemm(
    const unsigned short* __restrict__ Xb, const unsigned short* __restrict__ Yb,
    float* __restrict__ rowsum, float* __restrict__ colsum,
    float* __restrict__ diagsum) {
  extern __shared__ unsigned char sm[];  // [A:128K | B0:16K | B1:16K]

  const int tid = threadIdx.x;
  const int bid = blockIdx.x;
  // 512 blocks = 8 xcd x 8 panels x 8 colgroups
  const int xcd = bid & 7;
  const int panel = xcd * 8 + ((bid >> 3) & 7);   // 0..63 (256-row panel)
  const int colgroup = bid >> 6;                  // 0..7  (2048-col range)
  const int rowbase = panel * PANEL;
  const int colbase = colgroup * (NJ * JCOLS);

  const unsigned short* xb = Xb + (size_t)rowbase * DD;
  const unsigned short* ybg = Yb + (size_t)colbase * DD;

  const int wid = tid >> 6, lane = tid & 63;
  const int wm = wid >> 1, wn = wid & 1;   // wave = rows [wm*64,+64) x cols [wn*64,+64)
  const int lm = lane & 15, lk = lane >> 4;

  // ---- A fill: 8192 slots of 16B ([256 rows][32 slots]); 16 per thread.
  // LDS slot (row, s) holds source subslot g = s ^ (row&7) (involution).
#pragma unroll
  for (int p = 0; p < 16; ++p) {
    const int s = p * 512 + tid;
    const int row = s >> 5;
    const int g = (s & 31) ^ (row & 7);
    __builtin_amdgcn_global_load_lds(
        (const __attribute__((address_space(1))) unsigned*)(xb + row * DD + g * 8),
        (__attribute__((address_space(3))) unsigned*)(sm + s * 16), 16, 0, 0);
  }

  // ---- B staging offsets: 1024 slots of 16B ([128 cols][8 slots]); 2/thread.
  int bsrc[2], bdst[2];
#pragma unroll
  for (int p = 0; p < 2; ++p) {
    const int s = p * 512 + tid;
    const int row = s >> 3;                     // col index within j-tile
    const int g = (s & 7) ^ (row & 7);
    bsrc[p] = row * DD + g * 8;                 // + jn*JCOLS*DD + tn*BKT
    bdst[p] = A_BYTES + s * 16;                 // + buf*B_BYTES
  }

#define GLOADB(jn, tn, buf)                                                    \
  {                                                                            \
    _Pragma("unroll")                                                          \
    for (int p = 0; p < 2; ++p)                                                \
      __builtin_amdgcn_global_load_lds(                                        \
          (const __attribute__((address_space(1))) unsigned*)(ybg + (size_t)(jn) * (JCOLS * DD) + bsrc[p] + (tn) * BKT), \
          (__attribute__((address_space(3))) unsigned*)(sm + (buf) * B_BYTES + bdst[p]), \
          16, 0, 0);                                                           \
  }

  // A read: row = wm*64 + m*16 + lm; slot = (t*8 + kh*4 + lk) ^ (row&7)
#define RDA(m, t, kh)                                                          \
  (*(const bf16x8*)(sm + (wm * 64 + (m) * 16 + lm) * (DD * 2) +                \
                    ((((t) * 8 + (kh) * 4 + lk) ^ (lm & 7)) << 4)))
  // B read: col = wn*64 + nf*16 + lm; slot = (kh*4 + lk) ^ (col&7)
#define RDB(nf, kh, buf)                                                       \
  (*(const bf16x8*)(sm + A_BYTES + (buf) * B_BYTES +                           \
                    (wn * 64 + (nf) * 16 + lm) * (BKT * 2) +                   \
                    ((((kh) * 4 + lk) ^ (lm & 7)) << 4)))

  f32x4 acc[4][4] = {};
  float rowacc[4][4];
#pragma unroll
  for (int m = 0; m < 4; ++m)
#pragma unroll
    for (int r = 0; r < 4; ++r) rowacc[m][r] = 0.f;
  float dsum = 0.f;
  const float negC = -(SHIFT_C * LOG2E);

  // prologue: stage B(step 0) -> buf 0
  GLOADB(0, 0, 0);

  for (int j = 0; j < NJ; ++j) {
#pragma unroll
    for (int t = 0; t < NT; ++t) {
      __syncthreads();  // vmcnt/lgkm drain + barrier: buf[t&1] staged, prev reads done
      // stage next step into the other buffer (full-step runway)
      if (t < NT - 1) { GLOADB(j, t + 1, (t + 1) & 1); }
      else if (j < NJ - 1) { GLOADB(j + 1, 0, 0); }
      const int buf = t & 1;
      bf16x8 a0, b0[4];
#pragma unroll
      for (int kh = 0; kh < 2; ++kh) {
#pragma unroll
        for (int nf = 0; nf < 4; ++nf) b0[nf] = RDB(nf, kh, buf);
#pragma unroll
        for (int m = 0; m < 4; ++m) {
          a0 = RDA(m, t, kh);
#pragma unroll
          for (int nf = 0; nf < 4; ++nf)
            acc[m][nf] = __builtin_amdgcn_mfma_f32_16x16x32_bf16(a0, b0[nf], acc[m][nf], 0, 0, 0);
        }
      }
    }

    // ---- per-j epilogue (runs while next j's first stage is in flight) ----
    const int jc0 = colbase + j * JCOLS;
    float colacc[4] = {0.f, 0.f, 0.f, 0.f};
#pragma unroll
    for (int m = 0; m < 4; ++m)
#pragma unroll
      for (int nf = 0; nf < 4; ++nf)
#pragma unroll
        for (int r = 0; r < 4; ++r) {
          float e = EXP2F(__builtin_fmaf(acc[m][nf][r], LOG2E, negC));
          rowacc[m][r] += e;
          colacc[nf] += e;
        }
    // diagonal logits (only j-tiles overlapping the diagonal)
    if (jc0 < rowbase + PANEL && jc0 + JCOLS > rowbase) {
#pragma unroll
      for (int m = 0; m < 4; ++m)
#pragma unroll
        for (int nf = 0; nf < 4; ++nf)
#pragma unroll
          for (int r = 0; r < 4; ++r) {
            const int gr = rowbase + wm * 64 + m * 16 + lk * 4 + r;
            const int gc = jc0 + wn * 64 + nf * 16 + lm;
            if (gr == gc) dsum += acc[m][nf][r];
          }
    }
    // col sums: reduce across lk, atomic per column
#pragma unroll
    for (int nf = 0; nf < 4; ++nf) {
      float v = colacc[nf];
      v += __shfl_xor(v, 16);
      v += __shfl_xor(v, 32);
      if (lk == 0)
        atomicAdd(&colsum[jc0 + wn * 64 + nf * 16 + lm], v);
    }
    // reset acc for next j
    const f32x4 z4 = {0.f, 0.f, 0.f, 0.f};
#pragma unroll
    for (int m = 0; m < 4; ++m)
#pragma unroll
      for (int nf = 0; nf < 4; ++nf) acc[m][nf] = z4;
  }
#undef GLOADB
#undef RDA
#undef RDB

  // ---- block-end: diagonal + row sums (accumulated over all NJ tiles) ----
  {
    float d = dsum;
    d += __shfl_xor(d, 1);
    d += __shfl_xor(d, 2);
    d += __shfl_xor(d, 4);
    d += __shfl_xor(d, 8);
    d += __shfl_xor(d, 16);
    d += __shfl_xor(d, 32);
    if (lane == 0 && d != 0.f) atomicAdd(diagsum, d);
  }
#pragma unroll
  for (int m = 0; m < 4; ++m)
#pragma unroll
    for (int r = 0; r < 4; ++r) {
      float v = rowsum16_dpp(rowacc[m][r]);
      if (lm == 15)
        atomicAdd(&rowsum[rowbase + wm * 64 + m * 16 + lk * 4 + r], v);
    }
}

// ---------------- fallback (reg-staging, no ws bf16 buffers) ----------------
__global__ __launch_bounds__(256) void clip_main_fb(
    const float* __restrict__ X, const float* __restrict__ Y,
    float* __restrict__ rowsum, float* __restrict__ colsum,
    float* __restrict__ diagsum) {
  __shared__ __align__(16) unsigned char smem[2 * 128 * 64 * 2];
  unsigned char* smA = smem;
  unsigned char* smB = smem + 128 * 64 * 2;

  const int tid = threadIdx.x;
  const int bid = blockIdx.x;
  const int swz = (bid & 7) * 2048 + (bid >> 3);
  const int brow = swz >> 7;
  const int bcol = swz & 127;

  const float* xb = X + (size_t)brow * 128 * DD;
  const float* yb = Y + (size_t)bcol * 128 * DD;

  const int wid = tid >> 6, lane = tid & 63;
  const int wm = wid >> 1, wn = wid & 1;
  const int lm = lane & 15, lk = lane >> 4;

  f32x4 acc[4][4] = {};

  for (int ks = 0; ks < 4; ++ks) {
    const int kbase = ks * 64;
    if (ks) __syncthreads();
#pragma unroll
    for (int i = 0; i < 4; ++i) {
      const int c = tid + i * 256;
      const int row = c >> 3, slot = c & 7;
      const int boff = row * 128 + ((slot << 4) ^ ((row & 7) << 4));
      const float* ga = xb + row * DD + kbase + (slot << 3);
      float4 a0 = *(const float4*)ga;
      float4 a1 = *(const float4*)(ga + 4);
      uint4 pa = { pkbf(a0.x, a0.y), pkbf(a0.z, a0.w),
                   pkbf(a1.x, a1.y), pkbf(a1.z, a1.w) };
      *(uint4*)(smA + boff) = pa;
      const float* gb = yb + row * DD + kbase + (slot << 3);
      float4 b0 = *(const float4*)gb;
      float4 b1 = *(const float4*)(gb + 4);
      uint4 pb = { pkbf(b0.x, b0.y), pkbf(b0.z, b0.w),
                   pkbf(b1.x, b1.y), pkbf(b1.z, b1.w) };
      *(uint4*)(smB + boff) = pb;
    }
    __syncthreads();

#pragma unroll
    for (int kk = 0; kk < 2; ++kk) {
      const int kboff = kk * 64 + lk * 16;
      bf16x8 a[4], b[4];
#pragma unroll
      for (int m = 0; m < 4; ++m) {
        const int row = wm * 64 + m * 16 + lm;
        a[m] = *(const bf16x8*)(smA + row * 128 + (kboff ^ ((row & 7) << 4)));
      }
#pragma unroll
      for (int n = 0; n < 4; ++n) {
        const int row = wn * 64 + n * 16 + lm;
        b[n] = *(const bf16x8*)(smB + row * 128 + (kboff ^ ((row & 7) << 4)));
      }
#pragma unroll
      for (int m = 0; m < 4; ++m)
#pragma unroll
        for (int n = 0; n < 4; ++n)
          acc[m][n] = __builtin_amdgcn_mfma_f32_16x16x32_bf16(a[m], b[n], acc[m][n], 0, 0, 0);
    }
  }

  float rowacc[4][4];
  float colacc[4];
#pragma unroll
  for (int m = 0; m < 4; ++m)
#pragma unroll
    for (int r = 0; r < 4; ++r) rowacc[m][r] = 0.f;
#pragma unroll
  for (int n = 0; n < 4; ++n) colacc[n] = 0.f;

  const float negC = -(SHIFT_C * LOG2E);
#pragma unroll
  for (int m = 0; m < 4; ++m)
#pragma unroll
    for (int n = 0; n < 4; ++n)
#pragma unroll
      for (int r = 0; r < 4; ++r) {
        float e = EXP2F(__builtin_fmaf(acc[m][n][r], LOG2E, negC));
        rowacc[m][r] += e;
        colacc[n] += e;
      }

  if (brow == bcol && wm == wn) {
    float dsum = 0.f;
#pragma unroll
    for (int m = 0; m < 4; ++m)
#pragma unroll
      for (int n = 0; n < 4; ++n)
#pragma unroll
        for (int r = 0; r < 4; ++r) {
          const int rr = m * 16 + lk * 4 + r;
          const int cc = n * 16 + lm;
          if (rr == cc) dsum += acc[m][n][r];
        }
    dsum += __shfl_xor(dsum, 1);
    dsum += __shfl_xor(dsum, 2);
    dsum += __shfl_xor(dsum, 4);
    dsum += __shfl_xor(dsum, 8);
    dsum += __shfl_xor(dsum, 16);
    dsum += __shfl_xor(dsum, 32);
    if (lane == 0) atomicAdd(diagsum, dsum);
  }

#pragma unroll
  for (int m = 0; m < 4; ++m)
#pragma unroll
    for (int r = 0; r < 4; ++r) {
      float v = rowsum16_dpp(rowacc[m][r]);
      if (lm == 15)
        atomicAdd(&rowsum[brow * 128 + wm * 64 + m * 16 + lk * 4 + r], v);
    }
#pragma unroll
  for (int n = 0; n < 4; ++n) {
    float v = colacc[n];
    v += __shfl_xor(v, 16);
    v += __shfl_xor(v, 32);
    if (lk == 0)
      atomicAdd(&colsum[bcol * 128 + wn * 64 + n * 16 + lm], v);
  }
}

// ---------------- final reduction: parallel stats + tiny finisher ----------------
__global__ __launch_bounds__(256) void clip_stats(
    const float* __restrict__ rowsum, const float* __restrict__ colsum,
    float* __restrict__ partial) {
  __shared__ float sdata[4];
  const int i = blockIdx.x * 256 + threadIdx.x;
  float s = logf(rowsum[i]) + logf(colsum[i]);
  s += __shfl_xor(s, 1);
  s += __shfl_xor(s, 2);
  s += __shfl_xor(s, 4);
  s += __shfl_xor(s, 8);
  s += __shfl_xor(s, 16);
  s += __shfl_xor(s, 32);
  const int lane = threadIdx.x & 63, wv = threadIdx.x >> 6;
  if (lane == 0) sdata[wv] = s;
  __syncthreads();
  if (threadIdx.x == 0)
    atomicAdd(partial, sdata[0] + sdata[1] + sdata[2] + sdata[3]);
}

__global__ void clip_out(const float* __restrict__ partial,
                         const float* __restrict__ diagsum,
                         float* __restrict__ out) {
  if (threadIdx.x == 0)
    out[0] = (float)((double)SHIFT_C + (double)partial[0] * 0.5 / (double)NN
                     - (double)diagsum[0] / (double)NN);
}

extern "C" void kernel_launch(void* const* d_in, const int* in_sizes, int n_in,
                              void* d_out, int out_size, void* d_ws, size_t ws_size,
                              hipStream_t stream) {
  const float* X = (const float*)d_in[0];
  const float* Y = (const float*)d_in[1];

  const size_t bf16_bytes = (size_t)2 * NN * DD * sizeof(unsigned short);  // 16 MB
  const size_t stats_bytes = (size_t)(2 * NN + 2) * sizeof(float);

  if (ws_size >= bf16_bytes + stats_bytes) {
    unsigned short* Xb = (unsigned short*)d_ws;
    unsigned short* Yb = Xb + (size_t)NN * DD;
    float* rowsum = (float*)((unsigned char*)d_ws + bf16_bytes);
    float* colsum = rowsum + NN;
    float* diagsum = colsum + NN;
    float* partial = diagsum + 1;

    hipMemsetAsync(rowsum, 0, stats_bytes, stream);
    cvt_kernel<<<dim3(2 * NN * DD / 8 / 256), dim3(256), 0, stream>>>(X, Y, Xb, Yb);
    clip_gemm<<<dim3(512), dim3(THREADS), LDS_TOTAL, stream>>>(
        Xb, Yb, rowsum, colsum, diagsum);
    clip_stats<<<dim3(NN / 256), dim3(256), 0, stream>>>(rowsum, colsum, partial);
    clip_out<<<dim3(1), dim3(64), 0, stream>>>(partial, diagsum, (float*)d_out);
  } else {
    float* rowsum = (float*)d_ws;
    float* colsum = rowsum + NN;
    float* diagsum = colsum + NN;
    float* partial = diagsum + 1;
    hipMemsetAsync(d_ws, 0, stats_bytes, stream);
    clip_main_fb<<<dim3((NN / 128) * (NN / 128)), dim3(256), 0, stream>>>(
        X, Y, rowsum, colsum, diagsum);
    clip_stats<<<dim3(NN / 256), dim3(256), 0, stream>>>(rowsum, colsum, partial);
    clip_out<<<dim3(1), dim3(64), 0, stream>>>(partial, diagsum, (float*)d_out);
  }
}